// Round 4
// baseline (305.198 us; speedup 1.0000x reference)
//
#include <hip/hip_runtime.h>

#define N_NODES 50000
#define N_EDGES 625000
#define DIM 128

typedef __bf16 bf16x8 __attribute__((ext_vector_type(8)));
typedef __bf16 bf16x4 __attribute__((ext_vector_type(4)));
typedef float f32x4 __attribute__((ext_vector_type(4)));

__device__ __forceinline__ float bflo(unsigned u) { return __uint_as_float(u << 16); }
__device__ __forceinline__ float bfhi(unsigned u) { return __uint_as_float(u & 0xffff0000u); }

// ===========================================================================
// K1: fused [GEMM1 | histogram].
// Blocks [0, gemm_blocks): out h[i][:] = relu(feats[i] @ W_f^T + b_f) as bf16
//   (identical MFMA structure to R3, which passed).
// Blocks [gemm_blocks, ...): 4-edge/thread int4 histogram of dst into deg.
// ===========================================================================
__global__ __launch_bounds__(256) void gemm1_hist_k(
    const float* __restrict__ A_f32,
    const float* __restrict__ W,
    const float* __restrict__ bias,
    __bf16* __restrict__ out_bf16,
    const int* __restrict__ dst,
    int* __restrict__ deg,
    int gemm_blocks)
{
    const int t = threadIdx.x;

    if ((int)blockIdx.x >= gemm_blocks) {
        // ---- histogram path ----
        int idx = ((int)blockIdx.x - gemm_blocks) * 256 + t;
        if (idx < N_EDGES / 4) {
            int4 d4 = ((const int4*)dst)[idx];
            atomicAdd(&deg[d4.x], 1);
            atomicAdd(&deg[d4.y], 1);
            atomicAdd(&deg[d4.z], 1);
            atomicAdd(&deg[d4.w], 1);
        }
        return;
    }

    // ---- GEMM1 path ----
    __shared__ __align__(16) __bf16 w_lds[128 * 136];   // 34.8 KB

    for (int i = t; i < 4096; i += 256) {
        float4 f = ((const float4*)W)[i];
        int n = i >> 5;
        int k = (i & 31) << 2;
        __bf16* p = &w_lds[n * 136 + k];
        p[0] = (__bf16)f.x; p[1] = (__bf16)f.y;
        p[2] = (__bf16)f.z; p[3] = (__bf16)f.w;
    }
    __syncthreads();

    const int wave = t >> 6;
    const int lane = t & 63;
    const int q = lane >> 4;
    const int mr = lane & 15;

    const int m0 = blockIdx.x * 64 + wave * 16;
    int arow = m0 + mr;
    if (arow >= N_NODES) arow = N_NODES - 1;

    f32x4 acc[8] = {};

#pragma unroll
    for (int ks = 0; ks < 4; ++ks) {
        const int k0 = ks * 32 + q * 8;
        const float4* ap = (const float4*)&A_f32[(size_t)arow * DIM + k0];
        float4 a0 = ap[0], a1 = ap[1];
        bf16x8 af;
        af[0] = (__bf16)a0.x; af[1] = (__bf16)a0.y;
        af[2] = (__bf16)a0.z; af[3] = (__bf16)a0.w;
        af[4] = (__bf16)a1.x; af[5] = (__bf16)a1.y;
        af[6] = (__bf16)a1.z; af[7] = (__bf16)a1.w;
#pragma unroll
        for (int nt = 0; nt < 8; ++nt) {
            bf16x8 bfr = *(const bf16x8*)&w_lds[(nt * 16 + mr) * 136 + k0];
            acc[nt] = __builtin_amdgcn_mfma_f32_16x16x32_bf16(af, bfr, acc[nt], 0, 0, 0);
        }
    }

    __syncthreads();
    float* lds_f = (float*)w_lds;          // 64 x 132 fp32
#pragma unroll
    for (int nt = 0; nt < 8; ++nt)
#pragma unroll
        for (int r = 0; r < 4; ++r)
            lds_f[(wave * 16 + q * 4 + r) * 132 + nt * 16 + mr] = acc[nt][r];
    __syncthreads();

    const int nb = blockIdx.x * 64;
    for (int i = t; i < 2048; i += 256) {
        int lr = i >> 5;
        int cg = (i & 31) << 2;
        int grow = nb + lr;
        if (grow >= N_NODES) continue;
        float4 v = *(const float4*)&lds_f[lr * 132 + cg];
        float4 b4 = *(const float4*)&bias[cg];
        bf16x4 o;
        o[0] = (__bf16)fmaxf(v.x + b4.x, 0.f);
        o[1] = (__bf16)fmaxf(v.y + b4.y, 0.f);
        o[2] = (__bf16)fmaxf(v.z + b4.z, 0.f);
        o[3] = (__bf16)fmaxf(v.w + b4.w, 0.f);
        *(bf16x4*)&out_bf16[(size_t)grow * DIM + cg] = o;
    }
}

// ===========================================================================
// K2: single-block 1024-thread exclusive scan of deg[N_NODES] in place.
// Thread t owns elements [t*49, t*49+49); per-thread serial sum, block
// Hillis-Steele over 1024 partials, then per-thread write-back.
// ===========================================================================
__global__ __launch_bounds__(1024) void scan_k(int* __restrict__ deg)
{
    __shared__ int s[1024];
    const int t = threadIdx.x;
    const int CH = 49;                      // 1024*49 = 50176 >= 50000
    const int base = t * CH;

    int sum = 0;
    for (int j = 0; j < CH; ++j) {
        int i = base + j;
        if (i < N_NODES) sum += deg[i];
    }
    s[t] = sum;
    __syncthreads();
    for (int off = 1; off < 1024; off <<= 1) {
        int x = (t >= off) ? s[t - off] : 0;
        __syncthreads();
        s[t] += x;
        __syncthreads();
    }
    int run = s[t] - sum;                   // exclusive prefix of this chunk
    for (int j = 0; j < CH; ++j) {
        int i = base + j;
        if (i < N_NODES) {
            int v = deg[i];
            deg[i] = run;
            run += v;
        }
    }
}

// ===========================================================================
// K3: CSR fill, 4 edges/thread. After this, deg[d] = END offset of segment d.
// ===========================================================================
__global__ __launch_bounds__(256) void fill_k(
    const int* __restrict__ src, const int* __restrict__ dst,
    int* __restrict__ deg, int* __restrict__ edge_src)
{
    int idx = blockIdx.x * 256 + threadIdx.x;
    if (idx < N_EDGES / 4) {
        int4 s4 = ((const int4*)src)[idx];
        int4 d4 = ((const int4*)dst)[idx];
        edge_src[atomicAdd(&deg[d4.x], 1)] = s4.x;
        edge_src[atomicAdd(&deg[d4.y], 1)] = s4.y;
        edge_src[atomicAdd(&deg[d4.z], 1)] = s4.z;
        edge_src[atomicAdd(&deg[d4.w], 1)] = s4.w;
    }
}

// ===========================================================================
// K4: fused [neighbor-aggregate + GIN combine + GEMM2 + bias + relu].
// Lane l of wave w owns A-row m0+(l&15), k-chunk (l>>4)*8 (+32 per ks-step).
// Aggregation accumulates neighbors' h rows straight into A-fragment-layout
// fp32 registers (predicated loads; finished rows exec-masked off).
// Then af = bf16(1 + eps*h + agg) feeds the MFMA. No nbuf, no extra LDS.
// ===========================================================================
__global__ __launch_bounds__(256) void gemm2_agg_k(
    const __bf16* __restrict__ h,
    const int* __restrict__ deg,
    const int* __restrict__ edge_src,
    const float* __restrict__ eps_p,
    const float* __restrict__ W,
    const float* __restrict__ bias,
    float* __restrict__ out)
{
    __shared__ __align__(16) __bf16 w_lds[128 * 136];   // 34.8 KB

    const int t = threadIdx.x;

    for (int i = t; i < 4096; i += 256) {
        float4 f = ((const float4*)W)[i];
        int n = i >> 5;
        int k = (i & 31) << 2;
        __bf16* p = &w_lds[n * 136 + k];
        p[0] = (__bf16)f.x; p[1] = (__bf16)f.y;
        p[2] = (__bf16)f.z; p[3] = (__bf16)f.w;
    }
    __syncthreads();

    const int wave = t >> 6;
    const int lane = t & 63;
    const int q = lane >> 4;
    const int mr = lane & 15;

    const int m0 = blockIdx.x * 64 + wave * 16;
    int arow = m0 + mr;
    if (arow >= N_NODES) arow = N_NODES - 1;   // duplicate work, masked at store

    const int start = arow ? deg[arow - 1] : 0;
    const int end   = deg[arow];

    float agg[4][8] = {};

    int ei = start;
    while (__any(ei < end)) {
        bool p0 = ei < end;
        bool p1 = (ei + 1) < end;
        int s0 = 0, s1 = 0;
        if (p0) s0 = edge_src[ei];
        if (p1) s1 = edge_src[ei + 1];
        if (p0) {
#pragma unroll
            for (int ks = 0; ks < 4; ++ks) {
                uint4 r = *(const uint4*)&h[(size_t)s0 * DIM + ks * 32 + q * 8];
                agg[ks][0] += bflo(r.x); agg[ks][1] += bfhi(r.x);
                agg[ks][2] += bflo(r.y); agg[ks][3] += bfhi(r.y);
                agg[ks][4] += bflo(r.z); agg[ks][5] += bfhi(r.z);
                agg[ks][6] += bflo(r.w); agg[ks][7] += bfhi(r.w);
            }
        }
        if (p1) {
#pragma unroll
            for (int ks = 0; ks < 4; ++ks) {
                uint4 r = *(const uint4*)&h[(size_t)s1 * DIM + ks * 32 + q * 8];
                agg[ks][0] += bflo(r.x); agg[ks][1] += bfhi(r.x);
                agg[ks][2] += bflo(r.y); agg[ks][3] += bfhi(r.y);
                agg[ks][4] += bflo(r.z); agg[ks][5] += bfhi(r.z);
                agg[ks][6] += bflo(r.w); agg[ks][7] += bfhi(r.w);
            }
        }
        ei += 2;
    }

    const float eps = eps_p[0];
    f32x4 acc[8] = {};

#pragma unroll
    for (int ks = 0; ks < 4; ++ks) {
        const int k0 = ks * 32 + q * 8;
        uint4 hraw = *(const uint4*)&h[(size_t)arow * DIM + k0];
        float hf[8] = { bflo(hraw.x), bfhi(hraw.x), bflo(hraw.y), bfhi(hraw.y),
                        bflo(hraw.z), bfhi(hraw.z), bflo(hraw.w), bfhi(hraw.w) };
        bf16x8 af;
#pragma unroll
        for (int j = 0; j < 8; ++j)
            af[j] = (__bf16)(1.0f + eps * hf[j] + agg[ks][j]);
#pragma unroll
        for (int nt = 0; nt < 8; ++nt) {
            bf16x8 bfr = *(const bf16x8*)&w_lds[(nt * 16 + mr) * 136 + k0];
            acc[nt] = __builtin_amdgcn_mfma_f32_16x16x32_bf16(af, bfr, acc[nt], 0, 0, 0);
        }
    }

    // Epilogue: C layout col=lane&15, row=(lane>>4)*4+reg -> LDS -> coalesced
    __syncthreads();
    float* lds_f = (float*)w_lds;
#pragma unroll
    for (int nt = 0; nt < 8; ++nt)
#pragma unroll
        for (int r = 0; r < 4; ++r)
            lds_f[(wave * 16 + q * 4 + r) * 132 + nt * 16 + mr] = acc[nt][r];
    __syncthreads();

    const int nb = blockIdx.x * 64;
    for (int i = t; i < 2048; i += 256) {
        int lr = i >> 5;
        int cg = (i & 31) << 2;
        int grow = nb + lr;
        if (grow >= N_NODES) continue;
        float4 v = *(const float4*)&lds_f[lr * 132 + cg];
        float4 b4 = *(const float4*)&bias[cg];
        v.x = fmaxf(v.x + b4.x, 0.f);
        v.y = fmaxf(v.y + b4.y, 0.f);
        v.z = fmaxf(v.z + b4.z, 0.f);
        v.w = fmaxf(v.w + b4.w, 0.f);
        *(float4*)&out[(size_t)grow * DIM + cg] = v;
    }
}

extern "C" void kernel_launch(void* const* d_in, const int* in_sizes, int n_in,
                              void* d_out, int out_size, void* d_ws, size_t ws_size,
                              hipStream_t stream) {
    const float* feats = (const float*)d_in[0];
    const int*   src   = (const int*)d_in[1];
    const int*   dst   = (const int*)d_in[2];
    const float* W_f   = (const float*)d_in[3];
    const float* b_f   = (const float*)d_in[4];
    const float* W_phy = (const float*)d_in[5];
    const float* b_phy = (const float*)d_in[6];
    const float* eps   = (const float*)d_in[7];
    float* out = (float*)d_out;

    const size_t HN = (size_t)N_NODES * DIM;
    __bf16* h     = (__bf16*)d_ws;                      // 12.8 MB
    int* edge_src = (int*)(h + HN);                     // 2.5 MB
    int* deg      = edge_src + N_EDGES;                 // 200 KB

    const int gblocks = (N_NODES + 63) / 64;            // 782
    const int hblocks = (N_EDGES / 4 + 255) / 256;      // 611

    hipMemsetAsync(deg, 0, N_NODES * sizeof(int), stream);

    gemm1_hist_k<<<gblocks + hblocks, 256, 0, stream>>>(
        feats, W_f, b_f, h, dst, deg, gblocks);

    scan_k<<<1, 1024, 0, stream>>>(deg);

    fill_k<<<hblocks, 256, 0, stream>>>(src, dst, deg, edge_src);

    gemm2_agg_k<<<gblocks, 256, 0, stream>>>(
        h, deg, edge_src, eps, W_phy, b_phy, out);
}

// Round 5
// 217.553 us; speedup vs baseline: 1.4029x; 1.4029x over previous
//
#include <hip/hip_runtime.h>

#define N_NODES 50000
#define N_EDGES 625000
#define DIM 128

typedef __bf16 bf16x8 __attribute__((ext_vector_type(8)));
typedef __bf16 bf16x4 __attribute__((ext_vector_type(4)));
typedef float f32x4 __attribute__((ext_vector_type(4)));

__device__ __forceinline__ float bflo(unsigned u) { return __uint_as_float(u << 16); }
__device__ __forceinline__ float bfhi(unsigned u) { return __uint_as_float(u & 0xffff0000u); }

// ===========================================================================
// K1: fused [GEMM1 | histogram].  (unchanged from R4)
// ===========================================================================
__global__ __launch_bounds__(256) void gemm1_hist_k(
    const float* __restrict__ A_f32,
    const float* __restrict__ W,
    const float* __restrict__ bias,
    __bf16* __restrict__ out_bf16,
    const int* __restrict__ dst,
    int* __restrict__ deg,
    int gemm_blocks)
{
    const int t = threadIdx.x;

    if ((int)blockIdx.x >= gemm_blocks) {
        int idx = ((int)blockIdx.x - gemm_blocks) * 256 + t;
        if (idx < N_EDGES / 4) {
            int4 d4 = ((const int4*)dst)[idx];
            atomicAdd(&deg[d4.x], 1);
            atomicAdd(&deg[d4.y], 1);
            atomicAdd(&deg[d4.z], 1);
            atomicAdd(&deg[d4.w], 1);
        }
        return;
    }

    __shared__ __align__(16) __bf16 w_lds[128 * 136];   // 34.8 KB

    for (int i = t; i < 4096; i += 256) {
        float4 f = ((const float4*)W)[i];
        int n = i >> 5;
        int k = (i & 31) << 2;
        __bf16* p = &w_lds[n * 136 + k];
        p[0] = (__bf16)f.x; p[1] = (__bf16)f.y;
        p[2] = (__bf16)f.z; p[3] = (__bf16)f.w;
    }
    __syncthreads();

    const int wave = t >> 6;
    const int lane = t & 63;
    const int q = lane >> 4;
    const int mr = lane & 15;

    const int m0 = blockIdx.x * 64 + wave * 16;
    int arow = m0 + mr;
    if (arow >= N_NODES) arow = N_NODES - 1;

    f32x4 acc[8] = {};

#pragma unroll
    for (int ks = 0; ks < 4; ++ks) {
        const int k0 = ks * 32 + q * 8;
        const float4* ap = (const float4*)&A_f32[(size_t)arow * DIM + k0];
        float4 a0 = ap[0], a1 = ap[1];
        bf16x8 af;
        af[0] = (__bf16)a0.x; af[1] = (__bf16)a0.y;
        af[2] = (__bf16)a0.z; af[3] = (__bf16)a0.w;
        af[4] = (__bf16)a1.x; af[5] = (__bf16)a1.y;
        af[6] = (__bf16)a1.z; af[7] = (__bf16)a1.w;
#pragma unroll
        for (int nt = 0; nt < 8; ++nt) {
            bf16x8 bfr = *(const bf16x8*)&w_lds[(nt * 16 + mr) * 136 + k0];
            acc[nt] = __builtin_amdgcn_mfma_f32_16x16x32_bf16(af, bfr, acc[nt], 0, 0, 0);
        }
    }

    __syncthreads();
    float* lds_f = (float*)w_lds;          // 64 x 132 fp32
#pragma unroll
    for (int nt = 0; nt < 8; ++nt)
#pragma unroll
        for (int r = 0; r < 4; ++r)
            lds_f[(wave * 16 + q * 4 + r) * 132 + nt * 16 + mr] = acc[nt][r];
    __syncthreads();

    const int nb = blockIdx.x * 64;
    for (int i = t; i < 2048; i += 256) {
        int lr = i >> 5;
        int cg = (i & 31) << 2;
        int grow = nb + lr;
        if (grow >= N_NODES) continue;
        float4 v = *(const float4*)&lds_f[lr * 132 + cg];
        float4 b4 = *(const float4*)&bias[cg];
        bf16x4 o;
        o[0] = (__bf16)fmaxf(v.x + b4.x, 0.f);
        o[1] = (__bf16)fmaxf(v.y + b4.y, 0.f);
        o[2] = (__bf16)fmaxf(v.z + b4.z, 0.f);
        o[3] = (__bf16)fmaxf(v.w + b4.w, 0.f);
        *(bf16x4*)&out_bf16[(size_t)grow * DIM + cg] = o;
    }
}

// ===========================================================================
// K2a/K2b: two-step exclusive scan (R2's proven version — coalesced int4,
// 49 blocks; the R4 single-block scan was a 93 us serial-load disaster).
// ===========================================================================
__global__ __launch_bounds__(256) void scan_blocks_k(
    int* __restrict__ deg, int* __restrict__ blocksums)
{
    __shared__ int s[256];
    const int t = threadIdx.x;
    const int base = blockIdx.x * 1024 + t * 4;

    int v[4] = {0, 0, 0, 0};
    if (base + 3 < N_NODES) {
        int4 qd = *(const int4*)&deg[base];
        v[0] = qd.x; v[1] = qd.y; v[2] = qd.z; v[3] = qd.w;
    } else {
#pragma unroll
        for (int j = 0; j < 4; ++j)
            if (base + j < N_NODES) v[j] = deg[base + j];
    }
    int sum = v[0] + v[1] + v[2] + v[3];
    s[t] = sum;
    __syncthreads();
    for (int off = 1; off < 256; off <<= 1) {
        int x = (t >= off) ? s[t - off] : 0;
        __syncthreads();
        s[t] += x;
        __syncthreads();
    }
    if (t == 255) blocksums[blockIdx.x] = s[255];
    int run = s[t] - sum;
#pragma unroll
    for (int j = 0; j < 4; ++j) {
        int ex = run;
        run += v[j];
        if (base + j < N_NODES) deg[base + j] = ex;
    }
}

__global__ __launch_bounds__(256) void scan_add_k(
    int* __restrict__ deg, const int* __restrict__ blocksums, int nblocks)
{
    __shared__ int carry_s;
    const int t = threadIdx.x;
    if (t < 64) {
        int v = (t < blockIdx.x && t < nblocks) ? blocksums[t] : 0;
#pragma unroll
        for (int off = 32; off > 0; off >>= 1) v += __shfl_down(v, off, 64);
        if (t == 0) carry_s = v;
    }
    __syncthreads();
    const int carry = carry_s;
    if (carry == 0) return;
    const int base = blockIdx.x * 1024 + t * 4;
#pragma unroll
    for (int j = 0; j < 4; ++j)
        if (base + j < N_NODES) deg[base + j] += carry;
}

// ===========================================================================
// K3: CSR fill, 4 edges/thread. After this, deg[d] = END offset of segment d.
// ===========================================================================
__global__ __launch_bounds__(256) void fill_k(
    const int* __restrict__ src, const int* __restrict__ dst,
    int* __restrict__ deg, int* __restrict__ edge_src)
{
    int idx = blockIdx.x * 256 + threadIdx.x;
    if (idx < N_EDGES / 4) {
        int4 s4 = ((const int4*)src)[idx];
        int4 d4 = ((const int4*)dst)[idx];
        edge_src[atomicAdd(&deg[d4.x], 1)] = s4.x;
        edge_src[atomicAdd(&deg[d4.y], 1)] = s4.y;
        edge_src[atomicAdd(&deg[d4.z], 1)] = s4.z;
        edge_src[atomicAdd(&deg[d4.w], 1)] = s4.w;
    }
}

// ===========================================================================
// K4: fused [neighbor-aggregate + GIN combine + GEMM2 + bias + relu].
// (unchanged from R4)
// ===========================================================================
__global__ __launch_bounds__(256) void gemm2_agg_k(
    const __bf16* __restrict__ h,
    const int* __restrict__ deg,
    const int* __restrict__ edge_src,
    const float* __restrict__ eps_p,
    const float* __restrict__ W,
    const float* __restrict__ bias,
    float* __restrict__ out)
{
    __shared__ __align__(16) __bf16 w_lds[128 * 136];   // 34.8 KB

    const int t = threadIdx.x;

    for (int i = t; i < 4096; i += 256) {
        float4 f = ((const float4*)W)[i];
        int n = i >> 5;
        int k = (i & 31) << 2;
        __bf16* p = &w_lds[n * 136 + k];
        p[0] = (__bf16)f.x; p[1] = (__bf16)f.y;
        p[2] = (__bf16)f.z; p[3] = (__bf16)f.w;
    }
    __syncthreads();

    const int wave = t >> 6;
    const int lane = t & 63;
    const int q = lane >> 4;
    const int mr = lane & 15;

    const int m0 = blockIdx.x * 64 + wave * 16;
    int arow = m0 + mr;
    if (arow >= N_NODES) arow = N_NODES - 1;

    const int start = arow ? deg[arow - 1] : 0;
    const int end   = deg[arow];

    float agg[4][8] = {};

    int ei = start;
    while (__any(ei < end)) {
        bool p0 = ei < end;
        bool p1 = (ei + 1) < end;
        int s0 = 0, s1 = 0;
        if (p0) s0 = edge_src[ei];
        if (p1) s1 = edge_src[ei + 1];
        if (p0) {
#pragma unroll
            for (int ks = 0; ks < 4; ++ks) {
                uint4 r = *(const uint4*)&h[(size_t)s0 * DIM + ks * 32 + q * 8];
                agg[ks][0] += bflo(r.x); agg[ks][1] += bfhi(r.x);
                agg[ks][2] += bflo(r.y); agg[ks][3] += bfhi(r.y);
                agg[ks][4] += bflo(r.z); agg[ks][5] += bfhi(r.z);
                agg[ks][6] += bflo(r.w); agg[ks][7] += bfhi(r.w);
            }
        }
        if (p1) {
#pragma unroll
            for (int ks = 0; ks < 4; ++ks) {
                uint4 r = *(const uint4*)&h[(size_t)s1 * DIM + ks * 32 + q * 8];
                agg[ks][0] += bflo(r.x); agg[ks][1] += bfhi(r.x);
                agg[ks][2] += bflo(r.y); agg[ks][3] += bfhi(r.y);
                agg[ks][4] += bflo(r.z); agg[ks][5] += bfhi(r.z);
                agg[ks][6] += bflo(r.w); agg[ks][7] += bfhi(r.w);
            }
        }
        ei += 2;
    }

    const float eps = eps_p[0];
    f32x4 acc[8] = {};

#pragma unroll
    for (int ks = 0; ks < 4; ++ks) {
        const int k0 = ks * 32 + q * 8;
        uint4 hraw = *(const uint4*)&h[(size_t)arow * DIM + k0];
        float hf[8] = { bflo(hraw.x), bfhi(hraw.x), bflo(hraw.y), bfhi(hraw.y),
                        bflo(hraw.z), bfhi(hraw.z), bflo(hraw.w), bfhi(hraw.w) };
        bf16x8 af;
#pragma unroll
        for (int j = 0; j < 8; ++j)
            af[j] = (__bf16)(1.0f + eps * hf[j] + agg[ks][j]);
#pragma unroll
        for (int nt = 0; nt < 8; ++nt) {
            bf16x8 bfr = *(const bf16x8*)&w_lds[(nt * 16 + mr) * 136 + k0];
            acc[nt] = __builtin_amdgcn_mfma_f32_16x16x32_bf16(af, bfr, acc[nt], 0, 0, 0);
        }
    }

    __syncthreads();
    float* lds_f = (float*)w_lds;
#pragma unroll
    for (int nt = 0; nt < 8; ++nt)
#pragma unroll
        for (int r = 0; r < 4; ++r)
            lds_f[(wave * 16 + q * 4 + r) * 132 + nt * 16 + mr] = acc[nt][r];
    __syncthreads();

    const int nb = blockIdx.x * 64;
    for (int i = t; i < 2048; i += 256) {
        int lr = i >> 5;
        int cg = (i & 31) << 2;
        int grow = nb + lr;
        if (grow >= N_NODES) continue;
        float4 v = *(const float4*)&lds_f[lr * 132 + cg];
        float4 b4 = *(const float4*)&bias[cg];
        v.x = fmaxf(v.x + b4.x, 0.f);
        v.y = fmaxf(v.y + b4.y, 0.f);
        v.z = fmaxf(v.z + b4.z, 0.f);
        v.w = fmaxf(v.w + b4.w, 0.f);
        *(float4*)&out[(size_t)grow * DIM + cg] = v;
    }
}

extern "C" void kernel_launch(void* const* d_in, const int* in_sizes, int n_in,
                              void* d_out, int out_size, void* d_ws, size_t ws_size,
                              hipStream_t stream) {
    const float* feats = (const float*)d_in[0];
    const int*   src   = (const int*)d_in[1];
    const int*   dst   = (const int*)d_in[2];
    const float* W_f   = (const float*)d_in[3];
    const float* b_f   = (const float*)d_in[4];
    const float* W_phy = (const float*)d_in[5];
    const float* b_phy = (const float*)d_in[6];
    const float* eps   = (const float*)d_in[7];
    float* out = (float*)d_out;

    const size_t HN = (size_t)N_NODES * DIM;
    __bf16* h     = (__bf16*)d_ws;                      // 12.8 MB
    int* edge_src = (int*)(h + HN);                     // 2.5 MB
    int* deg      = edge_src + N_EDGES;                 // 200 KB
    int* blocksums = deg + N_NODES;                     // 196 B

    const int gblocks = (N_NODES + 63) / 64;            // 782
    const int hblocks = (N_EDGES / 4 + 255) / 256;      // 611
    const int nscan = (N_NODES + 1023) / 1024;          // 49

    hipMemsetAsync(deg, 0, N_NODES * sizeof(int), stream);

    gemm1_hist_k<<<gblocks + hblocks, 256, 0, stream>>>(
        feats, W_f, b_f, h, dst, deg, gblocks);

    scan_blocks_k<<<nscan, 256, 0, stream>>>(deg, blocksums);
    scan_add_k<<<nscan, 256, 0, stream>>>(deg, blocksums, nscan);

    fill_k<<<hblocks, 256, 0, stream>>>(src, dst, deg, edge_src);

    gemm2_agg_k<<<gblocks, 256, 0, stream>>>(
        h, deg, edge_src, eps, W_phy, b_phy, out);
}

// Round 6
// 213.175 us; speedup vs baseline: 1.4317x; 1.0205x over previous
//
#include <hip/hip_runtime.h>

#define N_NODES 50000
#define N_EDGES 625000
#define DIM 128

typedef __bf16 bf16x8 __attribute__((ext_vector_type(8)));
typedef __bf16 bf16x4 __attribute__((ext_vector_type(4)));
typedef float f32x4 __attribute__((ext_vector_type(4)));

__device__ __forceinline__ float bflo(unsigned u) { return __uint_as_float(u << 16); }
__device__ __forceinline__ float bfhi(unsigned u) { return __uint_as_float(u & 0xffff0000u); }

// ===========================================================================
// K1: fused [GEMM1 | histogram]. Histogram block 0 also zeroes h row N_NODES
// (the "zero row" used by K4's branchless gather for out-of-range edges).
// ===========================================================================
__global__ __launch_bounds__(256) void gemm1_hist_k(
    const float* __restrict__ A_f32,
    const float* __restrict__ W,
    const float* __restrict__ bias,
    __bf16* __restrict__ out_bf16,
    const int* __restrict__ dst,
    int* __restrict__ deg,
    int gemm_blocks)
{
    const int t = threadIdx.x;

    if ((int)blockIdx.x >= gemm_blocks) {
        // zero row h[N_NODES] (128 bf16 = 16 lanes x 8)
        if ((int)blockIdx.x == gemm_blocks && t < 16) {
            bf16x8 z = {};
            *(bf16x8*)&out_bf16[(size_t)N_NODES * DIM + t * 8] = z;
        }
        int idx = ((int)blockIdx.x - gemm_blocks) * 256 + t;
        if (idx < N_EDGES / 4) {
            int4 d4 = ((const int4*)dst)[idx];
            atomicAdd(&deg[d4.x], 1);
            atomicAdd(&deg[d4.y], 1);
            atomicAdd(&deg[d4.z], 1);
            atomicAdd(&deg[d4.w], 1);
        }
        return;
    }

    __shared__ __align__(16) __bf16 w_lds[128 * 136];   // 34.8 KB

    for (int i = t; i < 4096; i += 256) {
        float4 f = ((const float4*)W)[i];
        int n = i >> 5;
        int k = (i & 31) << 2;
        __bf16* p = &w_lds[n * 136 + k];
        p[0] = (__bf16)f.x; p[1] = (__bf16)f.y;
        p[2] = (__bf16)f.z; p[3] = (__bf16)f.w;
    }
    __syncthreads();

    const int wave = t >> 6;
    const int lane = t & 63;
    const int q = lane >> 4;
    const int mr = lane & 15;

    const int m0 = blockIdx.x * 64 + wave * 16;
    int arow = m0 + mr;
    if (arow >= N_NODES) arow = N_NODES - 1;

    f32x4 acc[8] = {};

#pragma unroll
    for (int ks = 0; ks < 4; ++ks) {
        const int k0 = ks * 32 + q * 8;
        const float4* ap = (const float4*)&A_f32[(size_t)arow * DIM + k0];
        float4 a0 = ap[0], a1 = ap[1];
        bf16x8 af;
        af[0] = (__bf16)a0.x; af[1] = (__bf16)a0.y;
        af[2] = (__bf16)a0.z; af[3] = (__bf16)a0.w;
        af[4] = (__bf16)a1.x; af[5] = (__bf16)a1.y;
        af[6] = (__bf16)a1.z; af[7] = (__bf16)a1.w;
#pragma unroll
        for (int nt = 0; nt < 8; ++nt) {
            bf16x8 bfr = *(const bf16x8*)&w_lds[(nt * 16 + mr) * 136 + k0];
            acc[nt] = __builtin_amdgcn_mfma_f32_16x16x32_bf16(af, bfr, acc[nt], 0, 0, 0);
        }
    }

    __syncthreads();
    float* lds_f = (float*)w_lds;          // 64 x 132 fp32
#pragma unroll
    for (int nt = 0; nt < 8; ++nt)
#pragma unroll
        for (int r = 0; r < 4; ++r)
            lds_f[(wave * 16 + q * 4 + r) * 132 + nt * 16 + mr] = acc[nt][r];
    __syncthreads();

    const int nb = blockIdx.x * 64;
    for (int i = t; i < 2048; i += 256) {
        int lr = i >> 5;
        int cg = (i & 31) << 2;
        int grow = nb + lr;
        if (grow >= N_NODES) continue;
        float4 v = *(const float4*)&lds_f[lr * 132 + cg];
        float4 b4 = *(const float4*)&bias[cg];
        bf16x4 o;
        o[0] = (__bf16)fmaxf(v.x + b4.x, 0.f);
        o[1] = (__bf16)fmaxf(v.y + b4.y, 0.f);
        o[2] = (__bf16)fmaxf(v.z + b4.z, 0.f);
        o[3] = (__bf16)fmaxf(v.w + b4.w, 0.f);
        *(bf16x4*)&out_bf16[(size_t)grow * DIM + cg] = o;
    }
}

// ===========================================================================
// K2a/K2b: two-step exclusive scan (proven R2/R5 version).
// ===========================================================================
__global__ __launch_bounds__(256) void scan_blocks_k(
    int* __restrict__ deg, int* __restrict__ blocksums)
{
    __shared__ int s[256];
    const int t = threadIdx.x;
    const int base = blockIdx.x * 1024 + t * 4;

    int v[4] = {0, 0, 0, 0};
    if (base + 3 < N_NODES) {
        int4 qd = *(const int4*)&deg[base];
        v[0] = qd.x; v[1] = qd.y; v[2] = qd.z; v[3] = qd.w;
    } else {
#pragma unroll
        for (int j = 0; j < 4; ++j)
            if (base + j < N_NODES) v[j] = deg[base + j];
    }
    int sum = v[0] + v[1] + v[2] + v[3];
    s[t] = sum;
    __syncthreads();
    for (int off = 1; off < 256; off <<= 1) {
        int x = (t >= off) ? s[t - off] : 0;
        __syncthreads();
        s[t] += x;
        __syncthreads();
    }
    if (t == 255) blocksums[blockIdx.x] = s[255];
    int run = s[t] - sum;
#pragma unroll
    for (int j = 0; j < 4; ++j) {
        int ex = run;
        run += v[j];
        if (base + j < N_NODES) deg[base + j] = ex;
    }
}

__global__ __launch_bounds__(256) void scan_add_k(
    int* __restrict__ deg, const int* __restrict__ blocksums, int nblocks)
{
    __shared__ int carry_s;
    const int t = threadIdx.x;
    if (t < 64) {
        int v = (t < blockIdx.x && t < nblocks) ? blocksums[t] : 0;
#pragma unroll
        for (int off = 32; off > 0; off >>= 1) v += __shfl_down(v, off, 64);
        if (t == 0) carry_s = v;
    }
    __syncthreads();
    const int carry = carry_s;
    if (carry == 0) return;
    const int base = blockIdx.x * 1024 + t * 4;
#pragma unroll
    for (int j = 0; j < 4; ++j)
        if (base + j < N_NODES) deg[base + j] += carry;
}

// ===========================================================================
// K3: CSR fill, 4 edges/thread. After this, deg[d] = END offset of segment d.
// ===========================================================================
__global__ __launch_bounds__(256) void fill_k(
    const int* __restrict__ src, const int* __restrict__ dst,
    int* __restrict__ deg, int* __restrict__ edge_src)
{
    int idx = blockIdx.x * 256 + threadIdx.x;
    if (idx < N_EDGES / 4) {
        int4 s4 = ((const int4*)src)[idx];
        int4 d4 = ((const int4*)dst)[idx];
        edge_src[atomicAdd(&deg[d4.x], 1)] = s4.x;
        edge_src[atomicAdd(&deg[d4.y], 1)] = s4.y;
        edge_src[atomicAdd(&deg[d4.z], 1)] = s4.z;
        edge_src[atomicAdd(&deg[d4.w], 1)] = s4.w;
    }
}

// ===========================================================================
// K4: fused [aggregate + GIN combine + GEMM2 + bias + relu].
// R6: branchless 4-edge-unrolled gather. Out-of-range edges read the zero
// row h[N_NODES] (uniform address -> broadcast) instead of exec-masking, so
// the compiler can keep 8-16 gather loads in flight (Little's law was the
// R5 limiter: VALUBusy 13%, occupancy 19%, nothing saturated).
// ===========================================================================
__global__ __launch_bounds__(256) void gemm2_agg_k(
    const __bf16* __restrict__ h,
    const int* __restrict__ deg,
    const int* __restrict__ edge_src,
    const float* __restrict__ eps_p,
    const float* __restrict__ W,
    const float* __restrict__ bias,
    float* __restrict__ out)
{
    __shared__ __align__(16) __bf16 w_lds[128 * 136];   // 34.8 KB

    const int t = threadIdx.x;

    for (int i = t; i < 4096; i += 256) {
        float4 f = ((const float4*)W)[i];
        int n = i >> 5;
        int k = (i & 31) << 2;
        __bf16* p = &w_lds[n * 136 + k];
        p[0] = (__bf16)f.x; p[1] = (__bf16)f.y;
        p[2] = (__bf16)f.z; p[3] = (__bf16)f.w;
    }
    __syncthreads();

    const int wave = t >> 6;
    const int lane = t & 63;
    const int q = lane >> 4;
    const int mr = lane & 15;

    const int m0 = blockIdx.x * 64 + wave * 16;
    int arow = m0 + mr;
    if (arow >= N_NODES) arow = N_NODES - 1;

    const int start = arow ? deg[arow - 1] : 0;
    const int end   = deg[arow];

    float agg[4][8] = {};
    const int ZROW = N_NODES;          // zero row (written by K1)

    int ei = start;
    while (__any(ei < end)) {
        // 4 edge indices, branchless (clamped loads; OOR -> zero row)
        int sidx[4];
#pragma unroll
        for (int u = 0; u < 4; ++u) {
            bool pu = (ei + u) < end;
            int eidx = pu ? (ei + u) : 0;
            int sv = edge_src[eidx];
            sidx[u] = pu ? sv : ZROW;
        }
        // pair 0: edges 0,1 — 8 uint4 in flight
        uint4 r[8];
#pragma unroll
        for (int ks = 0; ks < 4; ++ks) {
            r[ks]     = *(const uint4*)&h[(size_t)sidx[0] * DIM + ks * 32 + q * 8];
            r[4 + ks] = *(const uint4*)&h[(size_t)sidx[1] * DIM + ks * 32 + q * 8];
        }
#pragma unroll
        for (int u = 0; u < 2; ++u)
#pragma unroll
            for (int ks = 0; ks < 4; ++ks) {
                uint4 rv = r[u * 4 + ks];
                agg[ks][0] += bflo(rv.x); agg[ks][1] += bfhi(rv.x);
                agg[ks][2] += bflo(rv.y); agg[ks][3] += bfhi(rv.y);
                agg[ks][4] += bflo(rv.z); agg[ks][5] += bfhi(rv.z);
                agg[ks][6] += bflo(rv.w); agg[ks][7] += bfhi(rv.w);
            }
        // pair 1: edges 2,3
#pragma unroll
        for (int ks = 0; ks < 4; ++ks) {
            r[ks]     = *(const uint4*)&h[(size_t)sidx[2] * DIM + ks * 32 + q * 8];
            r[4 + ks] = *(const uint4*)&h[(size_t)sidx[3] * DIM + ks * 32 + q * 8];
        }
#pragma unroll
        for (int u = 0; u < 2; ++u)
#pragma unroll
            for (int ks = 0; ks < 4; ++ks) {
                uint4 rv = r[u * 4 + ks];
                agg[ks][0] += bflo(rv.x); agg[ks][1] += bfhi(rv.x);
                agg[ks][2] += bflo(rv.y); agg[ks][3] += bfhi(rv.y);
                agg[ks][4] += bflo(rv.z); agg[ks][5] += bfhi(rv.z);
                agg[ks][6] += bflo(rv.w); agg[ks][7] += bfhi(rv.w);
            }
        ei += 4;
    }

    const float eps = eps_p[0];
    f32x4 acc[8] = {};

#pragma unroll
    for (int ks = 0; ks < 4; ++ks) {
        const int k0 = ks * 32 + q * 8;
        uint4 hraw = *(const uint4*)&h[(size_t)arow * DIM + k0];
        float hf[8] = { bflo(hraw.x), bfhi(hraw.x), bflo(hraw.y), bfhi(hraw.y),
                        bflo(hraw.z), bfhi(hraw.z), bflo(hraw.w), bfhi(hraw.w) };
        bf16x8 af;
#pragma unroll
        for (int j = 0; j < 8; ++j)
            af[j] = (__bf16)(1.0f + eps * hf[j] + agg[ks][j]);
#pragma unroll
        for (int nt = 0; nt < 8; ++nt) {
            bf16x8 bfr = *(const bf16x8*)&w_lds[(nt * 16 + mr) * 136 + k0];
            acc[nt] = __builtin_amdgcn_mfma_f32_16x16x32_bf16(af, bfr, acc[nt], 0, 0, 0);
        }
    }

    __syncthreads();
    float* lds_f = (float*)w_lds;
#pragma unroll
    for (int nt = 0; nt < 8; ++nt)
#pragma unroll
        for (int r2 = 0; r2 < 4; ++r2)
            lds_f[(wave * 16 + q * 4 + r2) * 132 + nt * 16 + mr] = acc[nt][r2];
    __syncthreads();

    const int nb = blockIdx.x * 64;
    for (int i = t; i < 2048; i += 256) {
        int lr = i >> 5;
        int cg = (i & 31) << 2;
        int grow = nb + lr;
        if (grow >= N_NODES) continue;
        float4 v = *(const float4*)&lds_f[lr * 132 + cg];
        float4 b4 = *(const float4*)&bias[cg];
        v.x = fmaxf(v.x + b4.x, 0.f);
        v.y = fmaxf(v.y + b4.y, 0.f);
        v.z = fmaxf(v.z + b4.z, 0.f);
        v.w = fmaxf(v.w + b4.w, 0.f);
        *(float4*)&out[(size_t)grow * DIM + cg] = v;
    }
}

extern "C" void kernel_launch(void* const* d_in, const int* in_sizes, int n_in,
                              void* d_out, int out_size, void* d_ws, size_t ws_size,
                              hipStream_t stream) {
    const float* feats = (const float*)d_in[0];
    const int*   src   = (const int*)d_in[1];
    const int*   dst   = (const int*)d_in[2];
    const float* W_f   = (const float*)d_in[3];
    const float* b_f   = (const float*)d_in[4];
    const float* W_phy = (const float*)d_in[5];
    const float* b_phy = (const float*)d_in[6];
    const float* eps   = (const float*)d_in[7];
    float* out = (float*)d_out;

    const size_t HN = (size_t)(N_NODES + 1) * DIM;      // +1 zero row
    __bf16* h     = (__bf16*)d_ws;                      // 12.8 MB
    int* edge_src = (int*)(h + HN);                     // 2.5 MB
    int* deg      = edge_src + N_EDGES;                 // 200 KB
    int* blocksums = deg + N_NODES;                     // 196 B

    const int gblocks = (N_NODES + 63) / 64;            // 782
    const int hblocks = (N_EDGES / 4 + 255) / 256;      // 611
    const int nscan = (N_NODES + 1023) / 1024;          // 49

    hipMemsetAsync(deg, 0, N_NODES * sizeof(int), stream);

    gemm1_hist_k<<<gblocks + hblocks, 256, 0, stream>>>(
        feats, W_f, b_f, h, dst, deg, gblocks);

    scan_blocks_k<<<nscan, 256, 0, stream>>>(deg, blocksums);
    scan_add_k<<<nscan, 256, 0, stream>>>(deg, blocksums, nscan);

    fill_k<<<hblocks, 256, 0, stream>>>(src, dst, deg, edge_src);

    gemm2_agg_k<<<gblocks, 256, 0, stream>>>(
        h, deg, edge_src, eps, W_phy, b_phy, out);
}